// Round 11
// baseline (132.745 us; speedup 1.0000x reference)
//
#include <hip/hip_runtime.h>
#include <hip/hip_bf16.h>

#define N_PTS 65536
#define LOG2E 1.4426950408889634f
#define INV2PI 0.15915494309189535f

typedef __attribute__((ext_vector_type(8))) short short8;
typedef __attribute__((ext_vector_type(4))) short short4v;
typedef __attribute__((ext_vector_type(4))) float float4v;
typedef __attribute__((ext_vector_type(4))) unsigned int uint4v;

#if __has_builtin(__builtin_amdgcn_exp2f)
#define EXP2F(x) __builtin_amdgcn_exp2f(x)
#else
#define EXP2F(x) exp2f(x)
#endif

// cos on REVOLUTIONS (inputs pre-scaled by 1/2pi in prep): v_fract + v_cos.
#if __has_builtin(__builtin_amdgcn_cosf) && __has_builtin(__builtin_amdgcn_fractf)
#define COSR(x) __builtin_amdgcn_cosf(__builtin_amdgcn_fractf(x))
#else
#define COSR(x) __cosf((x) * 6.283185307179586f)
#endif

__device__ __forceinline__ short f2b(float f) {
    __hip_bfloat16 h = __float2bfloat16(f);
    return *(short*)&h;
}
__device__ __forceinline__ float b2f(short s) {
    __hip_bfloat16 h = *(__hip_bfloat16*)&s;
    return __bfloat162float(h);
}

// Cheap packed f32x2 -> bf16x2: round-half-away (bits + 0x8000, truncate).
// Same 0.5-ulp bound as RNE; validated R7/R10 (identical absmax).
__device__ __forceinline__ unsigned int pkbf(float a, float b) {
    unsigned int ua = __builtin_bit_cast(unsigned int, a) + 0x8000u;
    unsigned int ub = __builtin_bit_cast(unsigned int, b) + 0x8000u;
    return (ua >> 16) | (ub & 0xFFFF0000u);
}

// ---- producer MFMA: K=16 native if available, else masked 16x16x32.
#if __has_builtin(__builtin_amdgcn_mfma_f32_16x16x16bf16_1k)
#define HAVE_MFMA16 1
typedef short4v pafrag;
__device__ __forceinline__ float4v pmfma(pafrag a, pafrag b, float4v c) {
    return __builtin_amdgcn_mfma_f32_16x16x16bf16_1k(a, b, c, 0, 0, 0);
}
#else
#define HAVE_MFMA16 0
typedef short8 pafrag;
__device__ __forceinline__ float4v pmfma(pafrag a, pafrag b, float4v c) {
    return __builtin_amdgcn_mfma_f32_16x16x32_bf16(a, b, c, 0, 0, 0);
}
#endif

// A-fragment from a [rows][16] bf16 table: lane (q,c) -> row base+c, k-dims.
__device__ __forceinline__ pafrag ldrow(const short* base, int row16, int q, int c) {
#if HAVE_MFMA16
    return *(const pafrag*)(base + (size_t)(row16 + c) * 16 + 4 * q);
#else
    pafrag v = (pafrag)0;
    if (q < 2) v = *(const pafrag*)(base + (size_t)(row16 + c) * 16 + 8 * q);
    return v;
#endif
}
// B-fragment from x (f32 [n][16]): lane (q,c) -> col row, k-dims.
__device__ __forceinline__ pafrag mkxfrag(const float* x, size_t row, int q) {
#if HAVE_MFMA16
    float4v v = *(const float4v*)(x + row * 16 + 4 * q);
    pafrag a;
    a[0] = f2b(v.x); a[1] = f2b(v.y); a[2] = f2b(v.z); a[3] = f2b(v.w);
    return a;
#else
    pafrag a = (pafrag)0;
    if (q < 2) {
        const float4v* xp = (const float4v*)(x + row * 16 + 8 * q);
        float4v v0 = xp[0], v1 = xp[1];
        a[0] = f2b(v0.x); a[1] = f2b(v0.y); a[2] = f2b(v0.z); a[3] = f2b(v0.w);
        a[4] = f2b(v1.x); a[5] = f2b(v1.y); a[6] = f2b(v1.z); a[7] = f2b(v1.w);
    }
    return a;
#endif
}

// K-permutation: within each 32-row group, storage row p holds source row
// perm(p). Chunk A (p<16) -> m {0-3,8-11,16-19,24-27}; chunk B -> +4.
// Producer D-reg r at lane q (chunk A row 4q+r) => m = 8q+r; chunk B => 8q+4+r.
// So [dA[0..3], dB[0..3]] at lane q == consumer B-fragment k = 8q..8q+7.
__device__ __forceinline__ int permrow(int p) {
    return ((p & 12) << 1) + (p & 3) + ((p >> 4) << 2);
}

// ---------------- prep (unchanged) ----------------
// ws layout (bytes):
//   zb   [1024][16] bf16  @ 0        row-PERMUTED bf16(log2e * z)
//   FbB  [512][16] bf16   @ 32768    row-PERMUTED bf16(F^T / 2pi)  (rows = o*64+l)
//   BWd  [64][512] bf16   @ 49152    block-diag sqrt(2/64)*pw (natural cols)
//   Wtb  [64][1024] bf16  @ 114688   bf16(W) (natural cols)
//   nz2P [1024] f32       @ 245760   PERMUTED  -0.5*log2e*||bf16(z_m)||^2
//   phP  [512] f32        @ 249856   PERMUTED  phases / 2pi
__global__ __launch_bounds__(256) void prep_kernel(
    const float* __restrict__ z, const float* __restrict__ W,
    const float* __restrict__ F, const float* __restrict__ pw,
    const float* __restrict__ ph,
    short* __restrict__ zb, short* __restrict__ FbB,
    short* __restrict__ BWd, short* __restrict__ Wtb,
    float* __restrict__ nz2P, float* __restrict__ phP)
{
    int t = blockIdx.x * 256 + threadIdx.x;
    if (t < 16384) {
        int row = t >> 4, i = t & 15;
        int src = (row & ~31) + permrow(row & 31);
        zb[t] = f2b(LOG2E * z[src * 16 + i]);
    } else if (t < 17408) {
        int m = t - 16384;
        int src = (m & ~31) + permrow(m & 31);
        const float4v* zp = (const float4v*)(z + (size_t)src * 16);
        float s = 0.f;
        #pragma unroll
        for (int k = 0; k < 4; k++) {
            float4v v = zp[k];
            float a0 = b2f(f2b(v.x)), a1 = b2f(f2b(v.y));
            float a2 = b2f(f2b(v.z)), a3 = b2f(f2b(v.w));
            s += a0 * a0 + a1 * a1 + a2 * a2 + a3 * a3;
        }
        nz2P[m] = -(0.5f * LOG2E * s);
    } else if (t < 25600) {
        int p = t - 17408;
        int row = p >> 4, i = p & 15;
        int srow = (row & ~31) + permrow(row & 31);
        int o = srow >> 6, l = srow & 63;
        FbB[p] = f2b(INV2PI * F[o * 1024 + i * 64 + l]);
    } else if (t < 58368) {
        int p = t - 25600;
        int so = p >> 9, ol = p & 511, o = ol >> 6;
        float v = ((so & 7) == o) ? 0.17677669529663687f * pw[so * 64 + (ol & 63)] : 0.f;
        BWd[p] = f2b(v);
    } else if (t < 123904) {
        int p = t - 58368;
        Wtb[p] = f2b(W[p]);
    } else {
        int j = t - 123904;                    // 512 phases
        int sj = (j & ~31) + permrow(j & 31);
        phP[j] = INV2PI * ph[sj];
    }
}

// ---- producer: compute P subchunk (32 m) for 32 n, write swizzled LDS ----
// LDS tile: [32 n-rows][128 k-shorts] = 256B rows, 16 slots of 16B.
// phys_slot = (4s + q) ^ (c & 7): write (s=w) and read use the same formula;
// both are 2-way bank-aliased only (= free, m136).
template<bool ISCOS>
__device__ __forceinline__ void produceP(
    short* buf, const short* __restrict__ tbl, const float* __restrict__ cvec,
    int base, const pafrag* ax, int q, int c, int w)
{
    const int m0 = base + w * 32;
    pafrag bA = ldrow(tbl, m0, q, c);
    pafrag bB = ldrow(tbl, m0 + 16, q, c);
    float4v c0A = *(const float4v*)(cvec + m0 + 4 * q);
    float4v c0B = *(const float4v*)(cvec + m0 + 16 + 4 * q);
    #pragma unroll
    for (int nt = 0; nt < 2; nt++) {
        float4v dA = pmfma(bA, ax[nt], c0A);
        float4v dB = pmfma(bB, ax[nt], c0B);
        uint4v u;
        if (ISCOS) {
            u[0] = pkbf(COSR(dA[0]), COSR(dA[1]));
            u[1] = pkbf(COSR(dA[2]), COSR(dA[3]));
            u[2] = pkbf(COSR(dB[0]), COSR(dB[1]));
            u[3] = pkbf(COSR(dB[2]), COSR(dB[3]));
        } else {
            u[0] = pkbf(EXP2F(dA[0]), EXP2F(dA[1]));
            u[1] = pkbf(EXP2F(dA[2]), EXP2F(dA[3]));
            u[2] = pkbf(EXP2F(dB[0]), EXP2F(dB[1]));
            u[3] = pkbf(EXP2F(dB[2]), EXP2F(dB[3]));
        }
        int row = 16 * nt + c;
        int slot = (4 * w + q) ^ (c & 7);
        *(uint4v*)((char*)buf + row * 256 + slot * 16) = u;
    }
}

// ---- consumer: my 16 so-rows x 32 n over one 128-m group from LDS ----
__device__ __forceinline__ void consumeP(
    const short* buf, const short* __restrict__ wtab, int wstride, int base,
    float4v* acc, int q, int c, int w)
{
    #pragma unroll
    for (int s = 0; s < 4; s++) {
        short8 aw = *(const short8*)(wtab + (size_t)(16 * w + c) * wstride + base + s * 32 + q * 8);
        #pragma unroll
        for (int nt = 0; nt < 2; nt++) {
            int row = 16 * nt + c;
            int slot = (4 * s + q) ^ (c & 7);
            short8 pb = *(const short8*)((const char*)buf + row * 256 + slot * 16);
            acc[nt] = __builtin_amdgcn_mfma_f32_16x16x32_bf16(aw, pb, acc[nt], 0, 0, 0);
        }
    }
}

// ---------------- fused: so-split consumers, LDS-shared P, acc = 8 regs ----
// n-block 32, grid 2048, 4 waves. Producer: wave w computes P subchunk s=w
// of each 128-m group (same K-partition/tables/math as R10) into a
// double-buffered 8KB LDS tile. Consumer: wave w owns so-rows 16w..16w+15
// over FULL K -> acc[2] = 8 AGPR, aw loads 1/4, direct disjoint stores
// (no epilogue reduction). One barrier per group (produce g+1 || consume g).
// launch_bounds(256,6): reg cap 85 -> target 6 blocks/CU (24 waves/CU).
__global__ __launch_bounds__(256, 6) void fused_kernel(
    const float* __restrict__ x,
    const short* __restrict__ zb, const short* __restrict__ FbB,
    const short* __restrict__ BWd, const short* __restrict__ Wtb,
    const float* __restrict__ nz2P, const float* __restrict__ phP,
    float* __restrict__ out)
{
    __shared__ __align__(16) short Pt[2][32 * 128];   // 2 x 8KB
    __shared__ float x2c[32];

    const int tid = threadIdx.x;
    const int lane = tid & 63, w = tid >> 6;
    const int q = lane >> 4, c = lane & 15;
    const int n0 = blockIdx.x * 32;

    if (tid < 32) {
        float s = 0.f;
        const float4v* xr = (const float4v*)(x + (size_t)(n0 + tid) * 16);
        #pragma unroll
        for (int k = 0; k < 4; k++) {
            float4v v = xr[k];
            float a0 = b2f(f2b(v.x)), a1 = b2f(f2b(v.y));
            float a2 = b2f(f2b(v.z)), a3 = b2f(f2b(v.w));
            s += a0 * a0 + a1 * a1 + a2 * a2 + a3 * a3;
        }
        x2c[tid] = 0.5f * LOG2E * s;
    }

    // x B-fragments for the 2 n-groups (identical across waves by design)
    pafrag ax[2];
    #pragma unroll
    for (int nt = 0; nt < 2; nt++)
        ax[nt] = mkxfrag(x, (size_t)(n0 + nt * 16 + c), q);

    float4v acc[2];
    acc[0] = (float4v)(0.f);
    acc[1] = (float4v)(0.f);

    // prologue: produce data group 0 into buf0
    produceP<false>(&Pt[0][0], zb, nz2P, 0, ax, q, c, w);
    __syncthreads();   // covers x2c + buf0

    // ============ data: 8 groups of 128 m ============
    #pragma unroll 2
    for (int g = 0; g < 8; g++) {
        if (g < 7)
            produceP<false>(&Pt[(g + 1) & 1][0], zb, nz2P, (g + 1) * 128, ax, q, c, w);
        else
            produceP<true>(&Pt[0][0], FbB, phP, 0, ax, q, c, w);   // prior g=0 -> buf (8&1)=0
        consumeP(&Pt[g & 1][0], Wtb, 1024, g * 128, acc, q, c, w);
        __syncthreads();
    }

    // scale data part by exp2(-x2[n])
    #pragma unroll
    for (int nt = 0; nt < 2; nt++) {
        float sxv = EXP2F(-x2c[16 * nt + c]);
        acc[nt] *= sxv;
    }

    // ============ prior: 4 groups of 128 l ============
    #pragma unroll 2
    for (int g = 0; g < 4; g++) {
        const int G = 8 + g;
        if (g < 3)
            produceP<true>(&Pt[(G + 1) & 1][0], FbB, phP, (g + 1) * 128, ax, q, c, w);
        consumeP(&Pt[G & 1][0], BWd, 512, g * 128, acc, q, c, w);
        __syncthreads();
    }

    // ============ direct store: wave owns so-rows 16w..16w+15 ============
    #pragma unroll
    for (int nt = 0; nt < 2; nt++)
        #pragma unroll
        for (int r = 0; r < 4; r++)
            out[(size_t)(16 * w + 4 * q + r) * N_PTS + n0 + 16 * nt + c] = acc[nt][r];
}

extern "C" void kernel_launch(void* const* d_in, const int* in_sizes, int n_in,
                              void* d_out, int out_size, void* d_ws, size_t ws_size,
                              hipStream_t stream) {
    const float* x  = (const float*)d_in[0];   // [65536][16]
    const float* z  = (const float*)d_in[1];   // [1024][16]
    const float* W  = (const float*)d_in[2];   // [8][8][1024] = [64][1024]
    const float* F  = (const float*)d_in[3];   // [8][16][64]
    const float* ph = (const float*)d_in[4];   // [8][64]
    const float* pw = (const float*)d_in[5];   // [8][8][64] = [64][64]
    float* out = (float*)d_out;                // [64][65536]

    char* ws = (char*)d_ws;
    short* zb   = (short*)(ws);            // 32768 B
    short* FbB  = (short*)(ws + 32768);    // 16384 B
    short* BWd  = (short*)(ws + 49152);    // 65536 B
    short* Wtb  = (short*)(ws + 114688);   // 131072 B
    float* nz2P = (float*)(ws + 245760);   // 4096 B
    float* phP  = (float*)(ws + 249856);   // 2048 B

    prep_kernel<<<486, 256, 0, stream>>>(z, W, F, pw, ph, zb, FbB, BWd, Wtb, nz2P, phP);
    fused_kernel<<<2048, 256, 0, stream>>>(x, zb, FbB, BWd, Wtb, nz2P, phP, out);
}